// Round 3
// baseline (565.496 us; speedup 1.0000x reference)
//
#include <hip/hip_runtime.h>
#include <cmath>

#define B_  4
#define C_  512
#define N_  16384
#define H_  8
#define D_  64
#define C3_ 1536
#define EPS 1e-6f

#define PADT 136   // kvT [j][n] pad: 272B stride -> 2-way banks (free), 16B aligned
#define PADQ 72    // Qphi/Sb pad: 144B stride -> 2-way banks, 16B aligned
#define PADO 132   // f32 out-transpose pad

typedef __attribute__((ext_vector_type(8))) short bf16x8;
typedef __attribute__((ext_vector_type(4))) float f32x4;

typedef __attribute__((address_space(1))) const unsigned int as1_uint;
typedef __attribute__((address_space(3))) unsigned int as3_uint;

__device__ __forceinline__ void gld16(const void* g, void* l) {
    // async global->LDS, 16B/lane; LDS dest = wave-uniform base + lane*16
    __builtin_amdgcn_global_load_lds((as1_uint*)g, (as3_uint*)l, 16, 0, 0);
}

__device__ __forceinline__ ushort f2bf(float f) {
    union { float f; unsigned u; } c{f};
    unsigned r = (c.u + 0x7FFF + ((c.u >> 16) & 1)) >> 16;  // RNE
    return (ushort)r;
}
__device__ __forceinline__ float bf2f(ushort b) {
    union { unsigned u; float f; } c{(unsigned)b << 16};
    return c.f;
}
__device__ __forceinline__ float phi_f(float x) { return x > 0.f ? x + 1.f : __expf(x); }

// ---------------------------------------------------------------------------
// Generic transpose+cast: src f32 [R][Cc] -> dst bf16 [Cc][R].  Tiles 64x64.
// ---------------------------------------------------------------------------
__global__ __launch_bounds__(256) void k_transpose(
        const float* __restrict__ src, ushort* __restrict__ dst,
        int R, int Cc, long sStride, long dStride) {
    __shared__ ushort T[64][72];
    const long sb = (long)blockIdx.z * sStride;
    const long db = (long)blockIdx.z * dStride;
    const int c0 = blockIdx.x * 64, r0 = blockIdx.y * 64;
    const int t = threadIdx.x;
    const int ct = t & 15, rt = t >> 4;
    float4 v[4];
    #pragma unroll
    for (int k = 0; k < 4; ++k)
        v[k] = *(const float4*)(src + sb + (long)(r0 + rt * 4 + k) * Cc + c0 + ct * 4);
    #pragma unroll
    for (int j = 0; j < 4; ++j) {
        ushort pk[4];
        #pragma unroll
        for (int k = 0; k < 4; ++k) pk[k] = f2bf(((const float*)&v[k])[j]);
        *(uint2*)&T[ct * 4 + j][rt * 4] = *(uint2*)pk;
    }
    __syncthreads();
    const int c = t >> 2, rq = (t & 3) * 16;
    ushort* d = dst + db + (long)(c0 + c) * R + r0 + rq;
    *(int4*)(d)     = *(const int4*)&T[c][rq];
    *(int4*)(d + 8) = *(const int4*)&T[c][rq + 8];
}

// ---------------------------------------------------------------------------
// Fused kv GEMM (bf16 MFMA, global_load_lds staging, XOR-swizzled LDS) +
// phi + S = phi(K)^T V + ksum (via ones-column MFMA).
// grid (s=32, h=8, b=4) = 1024 WGs, 4 subtiles of 128 tokens each.
// ---------------------------------------------------------------------------
__global__ __launch_bounds__(256) void k_kv_s(
        const ushort* __restrict__ xt, const ushort* __restrict__ Wqt,
        const float* __restrict__ bqkv, float* __restrict__ S_g,
        float* __restrict__ ksum_g) {
    const int s = blockIdx.x, h = blockIdx.y, b = blockIdx.z;
    const int tid = threadIdx.x;
    const int w = tid >> 6, ln = tid & 63, lr = ln & 15, lq = ln >> 4;
    const int lrow = ln >> 3;                 // 0..7 staging row within 8-row issue
    const int swc = ((ln & 7) ^ lrow) * 8;    // swizzled global col chunk (bf16 elems)
    const int bh = b * H_ + h;

    __shared__ __align__(16) char smem[144 * PADT * 2];   // 39168 B
    ushort* sA = (ushort*)smem;                  // [128][64] staging (16 KB)
    ushort* sB = (ushort*)(smem + 16384);        // [128][64] staging (16 KB)
    ushort (*kvT)[PADT] = (ushort(*)[PADT])smem; // [144][.]: 0..63 kphi^T, 64..127 v^T, 128..143 ones
    __shared__ float biasL[128];

    if (tid < 128) {
        int col = tid < 64 ? (512 + h * 64 + tid) : (1024 + h * 64 + (tid - 64));
        biasL[tid] = bqkv[col];
    }
    {   // ones-tile rows 128..143 (row 128 = 1.0, rest 0) — beyond staging region
        int rr = 128 + (tid >> 4), cc = (tid & 15) * 8;
        ushort v = (tid >> 4) == 0 ? (ushort)0x3F80 : (ushort)0;
        ushort pk[8];
        #pragma unroll
        for (int j = 0; j < 8; ++j) pk[j] = v;
        *(int4*)&kvT[rr][cc] = *(int4*)pk;
    }

    // B (weight) per-lane global row pointers, fixed across subtiles
    const ushort* gB[4];
    #pragma unroll
    for (int q = 0; q < 4; ++q) {
        int j = w * 32 + q * 8 + lrow;
        int wr = j < 64 ? (512 + h * 64 + j) : (960 + h * 64 + j);
        gB[q] = Wqt + (long)wr * C_ + swc;
    }

    const f32x4 FZ = {0.f, 0.f, 0.f, 0.f};
    f32x4 Sacc[5] = {FZ, FZ, FZ, FZ, FZ};

    for (int it = 0; it < 4; ++it) {
        const int n0 = (s * 4 + it) * 128;
        const ushort* gA = xt + ((long)(b * N_ + n0 + w * 32 + lrow)) * C_ + swc;

        f32x4 acc[2][8];
        #pragma unroll
        for (int mi = 0; mi < 2; mi++)
            #pragma unroll
            for (int ji = 0; ji < 8; ji++) acc[mi][ji] = FZ;

        for (int kc = 0; kc < 8; ++kc) {
            const int c0 = kc * 64;
            __syncthreads();
            #pragma unroll
            for (int q = 0; q < 4; ++q) {
                gld16(gA + (long)(q * 8) * C_ + c0, sA + (w * 32 + q * 8) * 64);
                gld16(gB[q] + c0,                   sB + (w * 32 + q * 8) * 64);
            }
            __syncthreads();
            #pragma unroll
            for (int ks = 0; ks < 2; ++ks) {
                const int co = ((ks * 4 + lq) ^ (lr & 7)) * 8;
                bf16x8 a[2], bb[8];
                #pragma unroll
                for (int mi = 0; mi < 2; mi++)
                    a[mi] = *(const bf16x8*)(sA + (w * 32 + mi * 16 + lr) * 64 + co);
                #pragma unroll
                for (int ji = 0; ji < 8; ji++)
                    bb[ji] = *(const bf16x8*)(sB + (ji * 16 + lr) * 64 + co);
                #pragma unroll
                for (int mi = 0; mi < 2; mi++)
                    #pragma unroll
                    for (int ji = 0; ji < 8; ji++)
                        acc[mi][ji] = __builtin_amdgcn_mfma_f32_16x16x32_bf16(
                            a[mi], bb[ji], acc[mi][ji], 0, 0, 0);
            }
        }
        __syncthreads();
        // epilogue: bias + phi(k) -> kvT (overwrites sA/sB)
        #pragma unroll
        for (int mi = 0; mi < 2; mi++) {
            int nl = w * 32 + mi * 16 + lq * 4;
            #pragma unroll
            for (int ji = 0; ji < 8; ji++) {
                int j = ji * 16 + lr;
                float bs = biasL[j];
                ushort pk[4];
                #pragma unroll
                for (int r = 0; r < 4; r++) {
                    float vv = acc[mi][ji][r] + bs;
                    if (j < 64) vv = phi_f(vv);
                    pk[r] = f2bf(vv);
                }
                *(uint2*)&kvT[j][nl] = *(uint2*)pk;
            }
        }
        __syncthreads();
        // S rank-update (+ ksum via ones e-tile 4): wave w owns d-strip w*16..+16
        #pragma unroll
        for (int ks = 0; ks < 4; ++ks) {
            bf16x8 af = *(const bf16x8*)&kvT[w * 16 + lr][ks * 32 + lq * 8];
            #pragma unroll
            for (int e = 0; e < 5; e++) {
                bf16x8 bv = *(const bf16x8*)&kvT[64 + e * 16 + lr][ks * 32 + lq * 8];
                Sacc[e] = __builtin_amdgcn_mfma_f32_16x16x32_bf16(af, bv, Sacc[e], 0, 0, 0);
            }
        }
    }
    #pragma unroll
    for (int e = 0; e < 4; e++)
        #pragma unroll
        for (int r = 0; r < 4; r++)
            atomicAdd(&S_g[((long)bh * 64 + w * 16 + lq * 4 + r) * 64 + e * 16 + lr],
                      Sacc[e][r]);
    if (lr == 0) {
        #pragma unroll
        for (int r = 0; r < 4; r++)
            atomicAdd(&ksum_g[bh * 64 + w * 16 + lq * 4 + r], Sacc[4][r]);
    }
}

// ---------------------------------------------------------------------------
// S finalize: SbT[bh][160][64] bf16 hi (0..79: S^T rows + ksum row 64) + lo (80..159).
// ---------------------------------------------------------------------------
__global__ void k_sfin(const float* __restrict__ S_g, const float* __restrict__ ksum_g,
                       ushort* __restrict__ SbT) {
    int bh = blockIdx.x, t = threadIdx.x;
    for (int i = t; i < 5120; i += 256) {
        int e = i >> 6, d = i & 63;
        float v = (e < 64) ? S_g[(long)bh * 4096 + d * 64 + e]
                           : (e == 64 ? ksum_g[bh * 64 + d] : 0.f);
        ushort hi = f2bf(v);
        ushort lo = f2bf(v - bf2f(hi));
        SbT[(long)bh * 10240 + i] = hi;
        SbT[(long)bh * 10240 + 5120 + i] = lo;
    }
}

// ---------------------------------------------------------------------------
// Fused q GEMM (global_load_lds, swizzled) + phi + num/den (hi+lo S, ksum col)
// + attn store.  grid (nt=128, h=8, b=4).
// ---------------------------------------------------------------------------
__global__ __launch_bounds__(256) void k_q_attn(
        const ushort* __restrict__ xt, const ushort* __restrict__ Wqt,
        const float* __restrict__ bqkv, const ushort* __restrict__ SbT,
        ushort* __restrict__ attn) {
    const int nt = blockIdx.x, h = blockIdx.y, b = blockIdx.z;
    const int n0 = nt * 128;
    const int tid = threadIdx.x;
    const int w = tid >> 6, ln = tid & 63, lr = ln & 15, lq = ln >> 4;
    const int lrow = ln >> 3;
    const int swc = ((ln & 7) ^ lrow) * 8;
    const int bh = b * H_ + h;

    __shared__ __align__(16) char smem[24576];        // sA[128][64]+sB[64][64] | Sb[160][72]
    __shared__ __align__(16) ushort Qphi[128][PADQ];  // 18432 B
    __shared__ float denL[128];
    ushort* sA = (ushort*)smem;
    ushort* sB = (ushort*)(smem + 16384);
    ushort (*Sb)[PADQ] = (ushort(*)[PADQ])smem;

    float bias_q[4];
    #pragma unroll
    for (int ji = 0; ji < 4; ji++) bias_q[ji] = bqkv[h * 64 + ji * 16 + lr];

    const ushort* gA = xt + ((long)(b * N_ + n0 + w * 32 + lrow)) * C_ + swc;
    const ushort* gB[2];
    #pragma unroll
    for (int q = 0; q < 2; ++q)
        gB[q] = Wqt + (long)(h * 64 + w * 16 + q * 8 + lrow) * C_ + swc;

    const f32x4 FZ = {0.f, 0.f, 0.f, 0.f};
    f32x4 accq[2][4];
    #pragma unroll
    for (int mi = 0; mi < 2; mi++)
        #pragma unroll
        for (int ji = 0; ji < 4; ji++) accq[mi][ji] = FZ;

    for (int kc = 0; kc < 8; ++kc) {
        const int c0 = kc * 64;
        __syncthreads();
        #pragma unroll
        for (int q = 0; q < 4; ++q)
            gld16(gA + (long)(q * 8) * C_ + c0, sA + (w * 32 + q * 8) * 64);
        #pragma unroll
        for (int q = 0; q < 2; ++q)
            gld16(gB[q] + c0, sB + (w * 16 + q * 8) * 64);
        __syncthreads();
        #pragma unroll
        for (int ks = 0; ks < 2; ++ks) {
            const int co = ((ks * 4 + lq) ^ (lr & 7)) * 8;
            bf16x8 a[2], bb[4];
            #pragma unroll
            for (int mi = 0; mi < 2; mi++)
                a[mi] = *(const bf16x8*)(sA + (w * 32 + mi * 16 + lr) * 64 + co);
            #pragma unroll
            for (int ji = 0; ji < 4; ji++)
                bb[ji] = *(const bf16x8*)(sB + (ji * 16 + lr) * 64 + co);
            #pragma unroll
            for (int mi = 0; mi < 2; mi++)
                #pragma unroll
                for (int ji = 0; ji < 4; ji++)
                    accq[mi][ji] = __builtin_amdgcn_mfma_f32_16x16x32_bf16(
                        a[mi], bb[ji], accq[mi][ji], 0, 0, 0);
        }
    }
    // phi(q) -> Qphi[n][d]  (separate region; no barrier needed vs staging)
    #pragma unroll
    for (int mi = 0; mi < 2; mi++) {
        int nl = w * 32 + mi * 16 + lq * 4;
        #pragma unroll
        for (int ji = 0; ji < 4; ji++) {
            int d = ji * 16 + lr;
            #pragma unroll
            for (int r = 0; r < 4; r++)
                Qphi[nl + r][d] = f2bf(phi_f(accq[mi][ji][r] + bias_q[ji]));
        }
    }
    __syncthreads();
    // stage S hi+lo into freed staging region
    #pragma unroll
    for (int p = 0; p < 5; ++p) {
        int idx = p * 256 + tid;          // 0..1279 16B-chunks
        int row = idx >> 3, ch = (idx & 7) * 8;
        *(int4*)&Sb[row][ch] = *(const int4*)(SbT + (long)bh * 10240 + row * 64 + ch);
    }
    __syncthreads();
    // num (+den col 64) MFMA, hi+lo
    f32x4 accn[2][5];
    #pragma unroll
    for (int mi = 0; mi < 2; mi++)
        #pragma unroll
        for (int ei = 0; ei < 5; ei++) accn[mi][ei] = FZ;
    #pragma unroll
    for (int ks = 0; ks < 2; ++ks) {
        bf16x8 a[2];
        #pragma unroll
        for (int mi = 0; mi < 2; mi++)
            a[mi] = *(const bf16x8*)&Qphi[w * 32 + mi * 16 + lr][ks * 32 + lq * 8];
        #pragma unroll
        for (int ei = 0; ei < 5; ei++) {
            bf16x8 bhi = *(const bf16x8*)&Sb[ei * 16 + lr][ks * 32 + lq * 8];
            bf16x8 blo = *(const bf16x8*)&Sb[80 + ei * 16 + lr][ks * 32 + lq * 8];
            #pragma unroll
            for (int mi = 0; mi < 2; mi++) {
                accn[mi][ei] = __builtin_amdgcn_mfma_f32_16x16x32_bf16(
                    a[mi], bhi, accn[mi][ei], 0, 0, 0);
                accn[mi][ei] = __builtin_amdgcn_mfma_f32_16x16x32_bf16(
                    a[mi], blo, accn[mi][ei], 0, 0, 0);
            }
        }
    }
    if (lr == 0) {
        #pragma unroll
        for (int mi = 0; mi < 2; mi++)
            #pragma unroll
            for (int r = 0; r < 4; r++)
                denL[w * 32 + mi * 16 + lq * 4 + r] = accn[mi][4][r] + EPS;
    }
    __syncthreads();
    // attn = num/den -> Qphi (overwrite)
    #pragma unroll
    for (int mi = 0; mi < 2; mi++) {
        int nl = w * 32 + mi * 16 + lq * 4;
        #pragma unroll
        for (int ji = 0; ji < 4; ji++) {
            int e = ji * 16 + lr;
            #pragma unroll
            for (int r = 0; r < 4; r++)
                Qphi[nl + r][e] = f2bf(accn[mi][ji][r] / denL[nl + r]);
        }
    }
    __syncthreads();
    {   // coalesced store: attn[b][n][h*64..h*64+64)
        int row = tid >> 1, co = (tid & 1) * 32;
        const int4* sp = (const int4*)&Qphi[row][co];
        int4* dp = (int4*)(attn + ((long)(b * N_ + n0 + row)) * C_ + h * 64 + co);
        dp[0] = sp[0]; dp[1] = sp[1]; dp[2] = sp[2]; dp[3] = sp[3];
    }
}

// ---------------------------------------------------------------------------
// Proj GEMM (global_load_lds, swizzled): out[b][cout][n].
// grid (nt=512, jt=4), 128x128 tile, LDS-transposed coalesced f32 store.
// ---------------------------------------------------------------------------
__global__ __launch_bounds__(256) void k_proj(
        const ushort* __restrict__ attn, const ushort* __restrict__ Wpt,
        const float* __restrict__ bproj, float* __restrict__ out) {
    const int nt = blockIdx.x, jt = blockIdx.y;
    const int tid = threadIdx.x;
    const int w = tid >> 6, ln = tid & 63, lr = ln & 15, lq = ln >> 4;
    const int lrow = ln >> 3;
    const int swc = ((ln & 7) ^ lrow) * 8;
    const int b = nt >> 7;
    const int nloc = (nt & 127) * 128;

    __shared__ __align__(16) char smem[64 * PADO * 4];   // 33792 B
    ushort* sA = (ushort*)smem;
    ushort* sB = (ushort*)(smem + 16384);
    float (*outT)[PADO] = (float(*)[PADO])smem;

    const ushort* gA = attn + ((long)(nt * 128 + w * 32 + lrow)) * C_ + swc;
    const ushort* gB = Wpt + ((long)(jt * 128 + w * 32 + lrow)) * C_ + swc;

    const f32x4 FZ = {0.f, 0.f, 0.f, 0.f};
    f32x4 acc[2][8];
    #pragma unroll
    for (int mi = 0; mi < 2; mi++)
        #pragma unroll
        for (int ji = 0; ji < 8; ji++) acc[mi][ji] = FZ;

    for (int kc = 0; kc < 8; ++kc) {
        const int c0 = kc * 64;
        __syncthreads();
        #pragma unroll
        for (int q = 0; q < 4; ++q) {
            gld16(gA + (long)(q * 8) * C_ + c0, sA + (w * 32 + q * 8) * 64);
            gld16(gB + (long)(q * 8) * C_ + c0, sB + (w * 32 + q * 8) * 64);
        }
        __syncthreads();
        #pragma unroll
        for (int ks = 0; ks < 2; ++ks) {
            const int co = ((ks * 4 + lq) ^ (lr & 7)) * 8;
            bf16x8 a[2], bb[8];
            #pragma unroll
            for (int mi = 0; mi < 2; mi++)
                a[mi] = *(const bf16x8*)(sA + (w * 32 + mi * 16 + lr) * 64 + co);
            #pragma unroll
            for (int ji = 0; ji < 8; ji++)
                bb[ji] = *(const bf16x8*)(sB + (ji * 16 + lr) * 64 + co);
            #pragma unroll
            for (int mi = 0; mi < 2; mi++)
                #pragma unroll
                for (int ji = 0; ji < 8; ji++)
                    acc[mi][ji] = __builtin_amdgcn_mfma_f32_16x16x32_bf16(
                        a[mi], bb[ji], acc[mi][ji], 0, 0, 0);
        }
    }
    #pragma unroll
    for (int half = 0; half < 2; ++half) {
        __syncthreads();
        #pragma unroll
        for (int mi = 0; mi < 2; mi++) {
            int nl = w * 32 + mi * 16 + lq * 4;
            #pragma unroll
            for (int ji = 0; ji < 4; ji++) {
                int cl = ji * 16 + lr;
                float bs = bproj[jt * 128 + half * 64 + cl];
                f32x4 v = acc[mi][half * 4 + ji];
                #pragma unroll
                for (int r = 0; r < 4; r++) v[r] += bs;
                *(f32x4*)&outT[cl][nl] = v;
            }
        }
        __syncthreads();
        {
            int cl = tid >> 2, ch = (tid & 3) * 32;
            const float* sp = &outT[cl][ch];
            float* dp = out + ((long)(b * C_ + jt * 128 + half * 64 + cl)) * N_ + nloc + ch;
            #pragma unroll
            for (int k = 0; k < 8; ++k)
                ((float4*)dp)[k] = ((const float4*)sp)[k];
        }
    }
}

// ===========================================================================
// fp32 fallback (only if ws_size too small) — round-1 verified path
// ===========================================================================
__global__ __launch_bounds__(256) void kernelA_fb(
        const float* __restrict__ x, const float* __restrict__ Wqkv,
        const float* __restrict__ bqkv, float* __restrict__ S_g,
        float* __restrict__ ksum_g) {
    const int h = blockIdx.x;
    const int s = blockIdx.y;
    const int b = blockIdx.z;
    const int tid = threadIdx.x;
    const int tn = tid & 15;
    const int tj = tid >> 4;
    const int td = tid & 15;
    const int te = tid >> 4;

    __shared__ float As[16][64];
    __shared__ float Bs[16][128];
    __shared__ float kphi_s[64][64];
    __shared__ float v_s[64][64];

    float acc2[4][4];
    #pragma unroll
    for (int i = 0; i < 4; i++)
        #pragma unroll
        for (int j = 0; j < 4; j++) acc2[i][j] = 0.f;
    float ksum_r = 0.f;

    float bias_j[8];
    #pragma unroll
    for (int jj = 0; jj < 8; jj++) {
        int j = tj * 8 + jj;
        int col = (j < 64) ? (512 + h * 64 + j) : (1024 + h * 64 + (j - 64));
        bias_j[jj] = bqkv[col];
    }

    for (int it = 0; it < 8; ++it) {
        const int n0 = (s * 8 + it) * 64;
        float acc[4][8];
        #pragma unroll
        for (int i = 0; i < 4; i++)
            #pragma unroll
            for (int jj = 0; jj < 8; jj++) acc[i][jj] = 0.f;

        for (int kc = 0; kc < 32; ++kc) {
            const int c0 = kc * 16;
            __syncthreads();
            {
                int r = tid >> 4, n4 = (tid & 15) * 4;
                const float* src = x + ((size_t)b * C_ + (c0 + r)) * (size_t)N_ + n0 + n4;
                *(float4*)&As[r][n4] = *(const float4*)src;
            }
            #pragma unroll
            for (int part = 0; part < 2; ++part) {
                int idx = tid + part * 256;
                int r = idx >> 5;
                int j4 = (idx & 31) * 4;
                int col = (j4 < 64) ? (512 + h * 64 + j4) : (1024 + h * 64 + (j4 - 64));
                const float* src = Wqkv + (size_t)(c0 + r) * C3_ + col;
                *(float4*)&Bs[r][j4] = *(const float4*)src;
            }
            __syncthreads();
            #pragma unroll
            for (int k = 0; k < 16; ++k) {
                float a[4], bb[8];
                *(float4*)a      = *(const float4*)&As[k][tn * 4];
                *(float4*)&bb[0] = *(const float4*)&Bs[k][tj * 8];
                *(float4*)&bb[4] = *(const float4*)&Bs[k][tj * 8 + 4];
                #pragma unroll
                for (int i = 0; i < 4; i++)
                    #pragma unroll
                    for (int jj = 0; jj < 8; jj++)
                        acc[i][jj] = fmaf(a[i], bb[jj], acc[i][jj]);
            }
        }
        __syncthreads();
        if (tj < 8) {
            #pragma unroll
            for (int i = 0; i < 4; i++) {
                int n = tn * 4 + i;
                float tmp[8];
                #pragma unroll
                for (int jj = 0; jj < 8; jj++) tmp[jj] = phi_f(acc[i][jj] + bias_j[jj]);
                *(float4*)&kphi_s[n][tj * 8]     = *(float4*)&tmp[0];
                *(float4*)&kphi_s[n][tj * 8 + 4] = *(float4*)&tmp[4];
            }
        } else {
            #pragma unroll
            for (int i = 0; i < 4; i++) {
                int n = tn * 4 + i;
                float tmp[8];
                #pragma unroll
                for (int jj = 0; jj < 8; jj++) tmp[jj] = acc[i][jj] + bias_j[jj];
                *(float4*)&v_s[n][(tj - 8) * 8]     = *(float4*)&tmp[0];
                *(float4*)&v_s[n][(tj - 8) * 8 + 4] = *(float4*)&tmp[4];
            }
        }
        __syncthreads();
        #pragma unroll 4
        for (int n = 0; n < 64; ++n) {
            float a[4], bb[4];
            *(float4*)a  = *(const float4*)&kphi_s[n][td * 4];
            *(float4*)bb = *(const float4*)&v_s[n][te * 4];
            #pragma unroll
            for (int dd = 0; dd < 4; dd++)
                #pragma unroll
                for (int ee = 0; ee < 4; ee++)
                    acc2[dd][ee] = fmaf(a[dd], bb[ee], acc2[dd][ee]);
        }
        if (tid < 64) {
            float sum = 0.f;
            #pragma unroll 8
            for (int n = 0; n < 64; ++n) sum += kphi_s[n][tid];
            ksum_r += sum;
        }
    }

    const int bh = b * H_ + h;
    #pragma unroll
    for (int dd = 0; dd < 4; dd++)
        #pragma unroll
        for (int ee = 0; ee < 4; ee++)
            atomicAdd(&S_g[((size_t)bh * 64 + td * 4 + dd) * 64 + te * 4 + ee], acc2[dd][ee]);
    if (tid < 64) atomicAdd(&ksum_g[bh * 64 + tid], ksum_r);
}

__global__ __launch_bounds__(256) void kernelB_fb(
        const float* __restrict__ x, const float* __restrict__ Wqkv,
        const float* __restrict__ bqkv, const float* __restrict__ Wproj,
        const float* __restrict__ bproj, const float* __restrict__ S_g,
        const float* __restrict__ ksum_g, float* __restrict__ out) {
    const int nt = blockIdx.x;
    const int b  = blockIdx.y;
    const int n0 = nt * 16;
    const int tid = threadIdx.x;
    const int tn = tid & 3;
    const int tj = tid >> 2;

    __shared__ float QA[512][16];
    __shared__ float As[16][16];
    __shared__ float Bs2[16][256];
    __shared__ float SB[16][64];
    __shared__ float ksumL[512];
    __shared__ float denL[16];

    ksumL[tid]       = ksum_g[(size_t)b * 512 + tid];
    ksumL[tid + 256] = ksum_g[(size_t)b * 512 + tid + 256];

    for (int half = 0; half < 2; ++half) {
        float acc[4][4];
        #pragma unroll
        for (int i = 0; i < 4; i++)
            #pragma unroll
            for (int j = 0; j < 4; j++) acc[i][j] = 0.f;

        for (int kc = 0; kc < 32; ++kc) {
            const int c0 = kc * 16;
            __syncthreads();
            {
                int r = tid >> 4, n = tid & 15;
                As[r][n] = x[((size_t)b * C_ + c0 + r) * (size_t)N_ + n0 + n];
            }
            {
                int r = tid >> 4;
                int j0 = (tid & 15) * 16;
                const float* src = Wqkv + (size_t)(c0 + r) * C3_ + half * 256 + j0;
                float4* dst = (float4*)&Bs2[r][j0];
                #pragma unroll
                for (int q4 = 0; q4 < 4; q4++) dst[q4] = ((const float4*)src)[q4];
            }
            __syncthreads();
            #pragma unroll
            for (int k = 0; k < 16; ++k) {
                float a[4], bb[4];
                *(float4*)a  = *(const float4*)&As[k][tn * 4];
                *(float4*)bb = *(const float4*)&Bs2[k][tj * 4];
                #pragma unroll
                for (int i = 0; i < 4; i++)
                    #pragma unroll
                    for (int jj = 0; jj < 4; jj++)
                        acc[i][jj] = fmaf(a[i], bb[jj], acc[i][jj]);
            }
        }
        #pragma unroll
        for (int jj = 0; jj < 4; jj++) {
            int c = half * 256 + tj * 4 + jj;
            float bq = bqkv[c];
            float tmp[4];
            #pragma unroll
            for (int i = 0; i < 4; i++) tmp[i] = phi_f(acc[i][jj] + bq);
            *(float4*)&QA[c][tn * 4] = *(float4*)tmp;
        }
    }
    __syncthreads();

    for (int h = 0; h < H_; ++h) {
        if (tid < 16) {
            float d = 0.f;
            #pragma unroll 8
            for (int dd = 0; dd < 64; ++dd)
                d = fmaf(QA[h * 64 + dd][tid], ksumL[h * 64 + dd], d);
            denL[tid] = d + EPS;
        }
        float acc4[4] = {0.f, 0.f, 0.f, 0.f};
        for (int dc = 0; dc < 4; ++dc) {
            __syncthreads();
            {
                int r = tid >> 4, e4 = (tid & 15) * 4;
                *(float4*)&SB[r][e4] =
                    *(const float4*)&S_g[(((size_t)(b * H_ + h)) * 64 + dc * 16 + r) * 64 + e4];
            }
            __syncthreads();
            #pragma unroll
            for (int k = 0; k < 16; ++k) {
                float a[4];
                *(float4*)a = *(const float4*)&QA[h * 64 + dc * 16 + k][tn * 4];
                float bb = SB[k][tj];
                #pragma unroll
                for (int i = 0; i < 4; i++) acc4[i] = fmaf(a[i], bb, acc4[i]);
            }
        }
        __syncthreads();
        {
            float tmp[4];
            #pragma unroll
            for (int i = 0; i < 4; i++) tmp[i] = acc4[i] / denL[tn * 4 + i];
            *(float4*)&QA[h * 64 + tj][tn * 4] = *(float4*)tmp;
        }
        __syncthreads();
    }

    for (int half = 0; half < 2; ++half) {
        float acc[4][4];
        #pragma unroll
        for (int i = 0; i < 4; i++)
            #pragma unroll
            for (int j = 0; j < 4; j++) acc[i][j] = 0.f;

        for (int kc = 0; kc < 32; ++kc) {
            __syncthreads();
            {
                int r = tid >> 4;
                int j0 = (tid & 15) * 16;
                const float* src = Wproj + (size_t)(kc * 16 + r) * C_ + half * 256 + j0;
                float4* dst = (float4*)&Bs2[r][j0];
                #pragma unroll
                for (int q4 = 0; q4 < 4; q4++) dst[q4] = ((const float4*)src)[q4];
            }
            __syncthreads();
            #pragma unroll
            for (int k = 0; k < 16; ++k) {
                float a[4], bb[4];
                *(float4*)a  = *(const float4*)&QA[kc * 16 + k][tn * 4];
                *(float4*)bb = *(const float4*)&Bs2[k][tj * 4];
                #pragma unroll
                for (int i = 0; i < 4; i++)
                    #pragma unroll
                    for (int jj = 0; jj < 4; jj++)
                        acc[i][jj] = fmaf(a[i], bb[jj], acc[i][jj]);
            }
        }
        #pragma unroll
        for (int jj = 0; jj < 4; jj++) {
            int c = half * 256 + tj * 4 + jj;
            float bp = bproj[c];
            float tmp[4];
            #pragma unroll
            for (int i = 0; i < 4; i++) tmp[i] = acc[i][jj] + bp;
            *(float4*)&out[((size_t)b * C_ + c) * (size_t)N_ + n0 + tn * 4] = *(float4*)tmp;
        }
    }
}

// ===========================================================================
extern "C" void kernel_launch(void* const* d_in, const int* in_sizes, int n_in,
                              void* d_out, int out_size, void* d_ws, size_t ws_size,
                              hipStream_t stream) {
    const float* x     = (const float*)d_in[0];
    const float* Wqkv  = (const float*)d_in[1];
    const float* bqkv  = (const float*)d_in[2];
    const float* Wproj = (const float*)d_in[3];
    const float* bproj = (const float*)d_in[4];
    float* out = (float*)d_out;

    // ---- workspace layout (bytes) ----
    const size_t oS    = 0;                        // S_g f32 [32][64][64]
    const size_t oK    = oS + 524288;              // ksum f32 [32][64]
    const size_t oXT   = oK + 8192;                // xt bf16 [4][16384][512]
    const size_t oWq   = oXT + 67108864;           // Wq_t bf16 [1536][512]
    const size_t oWp   = oWq + 1572864;            // Wp_t bf16 [512][512]
    const size_t oSbT  = oWp + 524288;             // SbT bf16 [32][160][64]
    const size_t oAttn = oSbT + 655360;            // attn bf16 [4][16384][512]
    const size_t need  = oAttn + 67108864;

    float* S_g    = (float*)((char*)d_ws + oS);
    float* ksum_g = (float*)((char*)d_ws + oK);

    if (ws_size < need) {
        hipMemsetAsync(d_ws, 0, 532480, stream);
        kernelA_fb<<<dim3(H_, 32, B_), 256, 0, stream>>>(x, Wqkv, bqkv, S_g, ksum_g);
        kernelB_fb<<<dim3(N_ / 16, B_), 256, 0, stream>>>(x, Wqkv, bqkv, Wproj, bproj,
                                                          S_g, ksum_g, out);
        return;
    }

    ushort* xt   = (ushort*)((char*)d_ws + oXT);
    ushort* Wqt  = (ushort*)((char*)d_ws + oWq);
    ushort* Wpt  = (ushort*)((char*)d_ws + oWp);
    ushort* SbT  = (ushort*)((char*)d_ws + oSbT);
    ushort* attn = (ushort*)((char*)d_ws + oAttn);

    hipMemsetAsync(d_ws, 0, 532480, stream);  // S_g + ksum
    k_transpose<<<dim3(N_ / 64, C_ / 64, B_), 256, 0, stream>>>(
        x, xt, C_, N_, (long)C_ * N_, (long)N_ * C_);
    k_transpose<<<dim3(C3_ / 64, C_ / 64, 1), 256, 0, stream>>>(
        Wqkv, Wqt, C_, C3_, 0, 0);
    k_transpose<<<dim3(C_ / 64, C_ / 64, 1), 256, 0, stream>>>(
        Wproj, Wpt, C_, C_, 0, 0);
    k_kv_s<<<dim3(32, H_, B_), 256, 0, stream>>>(xt, Wqt, bqkv, S_g, ksum_g);
    k_sfin<<<dim3(B_ * H_), 256, 0, stream>>>(S_g, ksum_g, SbT);
    k_q_attn<<<dim3(N_ / 128, H_, B_), 256, 0, stream>>>(xt, Wqt, bqkv, SbT, attn);
    k_proj<<<dim3((B_ * N_) / 128, 4), 256, 0, stream>>>(attn, Wpt, bproj, out);
}